// Round 11
// baseline (383.765 us; speedup 1.0000x reference)
//
#include <hip/hip_runtime.h>
#include <math.h>

#define C        128
#define BLK      256
#define WPB      (BLK / 64)      // 4 waves per block
#define MAXSLOT  14              // 14 slots x 4 row-groups = 56 rows staged / segment
#define NROW     (4 * MAXSLOT)   // 56
#define WSTRIDE  68              // u32 per padded bf16 W row

__device__ __forceinline__ float4 f4add(float4 a, float4 b) {
    float4 r; r.x = a.x + b.x; r.y = a.y + b.y; r.z = a.z + b.z; r.w = a.w + b.w; return r;
}
__device__ __forceinline__ float4 f4shfl_xor(float4 v, int m) {
    float4 r;
    r.x = __shfl_xor(v.x, m, 64);
    r.y = __shfl_xor(v.y, m, 64);
    r.z = __shfl_xor(v.z, m, 64);
    r.w = __shfl_xor(v.w, m, 64);
    return r;
}
__device__ __forceinline__ float4 f4mask(float4 v, bool keep) {
    v.x = keep ? v.x : 0.f; v.y = keep ? v.y : 0.f;
    v.z = keep ? v.z : 0.f; v.w = keep ? v.w : 0.f;
    return v;
}
__device__ __forceinline__ float fast_tanh(float v) {
    const float t = __expf(2.0f * v);
    return 1.0f - 2.0f / (t + 1.0f);
}
__device__ __forceinline__ float fast_sigmoid(float v) {
    return 1.0f / (1.0f + __expf(-v));
}
// RNE-pack two fp32 into one u32 of bf16 (a -> low16, b -> high16)
__device__ __forceinline__ uint32_t pack2(float a, float b) {
    uint32_t ua = __float_as_uint(a), ub = __float_as_uint(b);
    ua = (ua + 0x7FFFu + ((ua >> 16) & 1u)) >> 16;
    ub = (ub + 0x7FFFu + ((ub >> 16) & 1u)) & 0xFFFF0000u;
    return ua | ub;
}
__device__ __forceinline__ float4 unpack4(uint32_t a, uint32_t b) {
    float4 v;
    v.x = __uint_as_float(a << 16);
    v.y = __uint_as_float(a & 0xFFFF0000u);
    v.z = __uint_as_float(b << 16);
    v.w = __uint_as_float(b & 0xFFFF0000u);
    return v;
}
// sum across the 16 lanes of this row-group; pure VALU (DPP row_ror tree)
__device__ __forceinline__ float row16_sum(float d) {
    d += __int_as_float(__builtin_amdgcn_update_dpp(0, __float_as_int(d), 0x128, 0xF, 0xF, true));
    d += __int_as_float(__builtin_amdgcn_update_dpp(0, __float_as_int(d), 0x124, 0xF, 0xF, true));
    d += __int_as_float(__builtin_amdgcn_update_dpp(0, __float_as_int(d), 0x122, 0xF, 0xF, true));
    d += __int_as_float(__builtin_amdgcn_update_dpp(0, __float_as_int(d), 0x121, 0xF, 0xF, true));
    return d;
}
__device__ __forceinline__ float dot8(float4 lo, float4 hi, float4 clo, float4 chi) {
    float a = lo.x * clo.x + lo.y * clo.y;
    float b = lo.z * clo.z + lo.w * clo.w;
    float c = hi.x * chi.x + hi.y * chi.y;
    float d = hi.z * chi.z + hi.w * chi.w;
    return (a + b) + (c + d);
}

extern "C" __global__ __launch_bounds__(BLK)
__attribute__((amdgpu_waves_per_eu(2, 2)))   // PIN 2 waves/EU: 256-VGPR budget; live set ~218
void cba_pipe14_kernel(const float* __restrict__ x,
                       const float* __restrict__ W,
                       const int* __restrict__ batch,
                       float* __restrict__ out,
                       int N, int B, int totalWaves)
{
    __shared__ uint32_t sWb[C * WSTRIDE];   // 34816 B : bf16 W, padded + quarter-rotated rows
    __shared__ float4   sMean[WPB * 32];    // 2048 B  : per-wave mean broadcast

    const int t    = threadIdx.x;
    const int lane = t & 63;
    const int wid  = t >> 6;       // wave in block 0..3
    const int rg   = lane >> 4;    // row-group / split-K quarter 0..3
    const int c16  = lane & 15;    // owns channels c16*8 .. c16*8+7

    // ---- one-time: W -> bf16 -> LDS ----
    const float2* W2 = (const float2*)W;
    for (int p = t; p < C * 64; p += BLK) {
        const int k = p >> 6, j = p & 63;
        const float2 wv = W2[p];
        sWb[k * WSTRIDE + ((j + ((k >> 5) << 3)) & 63)] = pack2(wv.x, wv.y);
    }
    __syncthreads();

    const int gw = blockIdx.x * WPB + wid;

    // ---- chunk-contiguous segment assignment ----
    const int qn = B / totalWaves;
    const int r  = B % totalWaves;
    const int segStart = gw * qn + (gw < r ? gw : r);
    const int myCnt    = qn + (gw < r ? 1 : 0);       // <= 25

    // ---- lane-parallel boundary search ----
    const int tl     = lane < myCnt ? lane : myCnt;
    const int target = segStart + tl;
    int lo_ = 0, hi_ = N;
    while (lo_ < hi_) {
        int mid = (lo_ + hi_) >> 1;
        if (batch[mid] < target) lo_ = mid + 1; else hi_ = mid;
    }
    const int bs = lo_;

    const float4* x4  = (const float4*)x;
    const int     Nm1 = N - 1;
    float4* mb = sMean + wid * 32;
    const int co = (((c16 << 2) + (rg << 3)) & 63);   // rotated W column offset

    // prefetch window: next segment's first 56 rows, fp32 (112 VGPR)
    float4 pl[MAXSLOT], ph[MAXSLOT];

#define ISSUE(sseg)                                                    \
    {                                                                  \
        _Pragma("unroll")                                              \
        for (int sl = 0; sl < MAXSLOT; ++sl) {                         \
            const int row = (sseg) + 4 * sl + rg;                      \
            const int rc  = row < Nm1 ? row : Nm1;                     \
            pl[sl] = x4[(size_t)rc * 32 + (c16 << 1)];                 \
            ph[sl] = x4[(size_t)rc * 32 + (c16 << 1) + 1];             \
        }                                                              \
    }

    int sCur = 0, eCur = 0;
    if (myCnt > 0) {
        sCur = __shfl(bs, 0, 64);
        eCur = __shfl(bs, 1, 64);
        ISSUE(sCur);                                   // prologue: segment 0 in flight
    }

    for (int k = 0; k < myCnt; ++k) {
        const int b   = segStart + k;
        const int s   = sCur;
        const int e   = eCur;
        const int cnt = e - s;

        // ======== consume prefetched rows: mask, fp32 sum, bf16-pack to regs ========
        uint4 rbPk[MAXSLOT];                           // 56 VGPR
        float4 alo = make_float4(0.f,0.f,0.f,0.f), ahi = alo;
#pragma unroll
        for (int sl = 0; sl < MAXSLOT; ++sl) {
            const bool valid = (s + 4 * sl + rg) < e;
            const float4 lo = f4mask(pl[sl], valid);
            const float4 hi = f4mask(ph[sl], valid);
            alo = f4add(alo, lo); ahi = f4add(ahi, hi);
            rbPk[sl].x = pack2(lo.x, lo.y); rbPk[sl].y = pack2(lo.z, lo.w);
            rbPk[sl].z = pack2(hi.x, hi.y); rbPk[sl].w = pack2(hi.z, hi.w);
        }
        // tail rows > 56: now 0.7% of segments — synchronous is fine
        for (int i = s + NROW + rg; i < e; i += 4) {
            alo = f4add(alo, x4[(size_t)i * 32 + (c16 << 1)]);
            ahi = f4add(ahi, x4[(size_t)i * 32 + (c16 << 1) + 1]);
        }

        // ======== issue prefetch for segment k+1 NOW; flies under GEMM + pass 2 ========
        if (k + 1 < myCnt) {
            sCur = __shfl(bs, k + 1, 64);
            eCur = __shfl(bs, k + 2, 64);
            ISSUE(sCur);
        }
        __builtin_amdgcn_sched_barrier(0);             // keep the loads above the compute

        // ======== mean (cross-row-group reduce) ========
        alo = f4add(alo, f4shfl_xor(alo, 16));
        alo = f4add(alo, f4shfl_xor(alo, 32));
        ahi = f4add(ahi, f4shfl_xor(ahi, 16));
        ahi = f4add(ahi, f4shfl_xor(ahi, 32));
        const float inv = 1.0f / (float)(cnt > 0 ? cnt : 1);
        if (lane < 16) {
            float4 mlo, mhi;
            mlo.x = alo.x*inv; mlo.y = alo.y*inv; mlo.z = alo.z*inv; mlo.w = alo.w*inv;
            mhi.x = ahi.x*inv; mhi.y = ahi.y*inv; mhi.z = ahi.z*inv; mhi.w = ahi.w*inv;
            mb[2 * c16]     = mlo;
            mb[2 * c16 + 1] = mhi;
        }
        // same-wave ds_write -> ds_read; compiler inserts lgkmcnt

        // ======== GEMM: c = tanh(mean @ W); quarter rg covers k in [32rg, 32rg+32) ========
        float4 plo = make_float4(0.f,0.f,0.f,0.f), phi = plo;
#pragma unroll
        for (int jq = 0; jq < 8; ++jq) {
            const float4 m4 = mb[(rg << 3) + jq];
            const int kb = (rg << 5) + (jq << 2);
            const uint4 u0 = *(const uint4*)&sWb[(kb + 0) * WSTRIDE + co];
            const uint4 u1 = *(const uint4*)&sWb[(kb + 1) * WSTRIDE + co];
            const uint4 u2 = *(const uint4*)&sWb[(kb + 2) * WSTRIDE + co];
            const uint4 u3 = *(const uint4*)&sWb[(kb + 3) * WSTRIDE + co];
#define FMA8(mm, uu)                                                          \
            {                                                                 \
                plo.x = fmaf(mm, __uint_as_float((uu).x << 16),        plo.x);\
                plo.y = fmaf(mm, __uint_as_float((uu).x & 0xFFFF0000u),plo.y);\
                plo.z = fmaf(mm, __uint_as_float((uu).y << 16),        plo.z);\
                plo.w = fmaf(mm, __uint_as_float((uu).y & 0xFFFF0000u),plo.w);\
                phi.x = fmaf(mm, __uint_as_float((uu).z << 16),        phi.x);\
                phi.y = fmaf(mm, __uint_as_float((uu).z & 0xFFFF0000u),phi.y);\
                phi.z = fmaf(mm, __uint_as_float((uu).w << 16),        phi.z);\
                phi.w = fmaf(mm, __uint_as_float((uu).w & 0xFFFF0000u),phi.w);\
            }
            FMA8(m4.x, u0); FMA8(m4.y, u1); FMA8(m4.z, u2); FMA8(m4.w, u3);
#undef FMA8
        }
        plo = f4add(plo, f4shfl_xor(plo, 16));
        plo = f4add(plo, f4shfl_xor(plo, 32));
        phi = f4add(phi, f4shfl_xor(phi, 16));
        phi = f4add(phi, f4shfl_xor(phi, 32));
        float4 clo, chi;
        clo.x = fast_tanh(plo.x); clo.y = fast_tanh(plo.y);
        clo.z = fast_tanh(plo.z); clo.w = fast_tanh(plo.w);
        chi.x = fast_tanh(phi.x); chi.y = fast_tanh(phi.y);
        chi.z = fast_tanh(phi.z); chi.w = fast_tanh(phi.w);

        // ======== pass 2: gates + h from bf16 regs; DPP-only row reduction ========
        float4 hlo = make_float4(0.f,0.f,0.f,0.f), hhi = hlo;
#pragma unroll
        for (int sl = 0; sl < MAXSLOT; ++sl) {
            const float4 lo = unpack4(rbPk[sl].x, rbPk[sl].y);
            const float4 hi = unpack4(rbPk[sl].z, rbPk[sl].w);
            float d = dot8(lo, hi, clo, chi);
            d = row16_sum(d);
            const float g = fast_sigmoid(d);           // masked rows staged as 0 -> g*0
            hlo.x = fmaf(g, lo.x, hlo.x); hlo.y = fmaf(g, lo.y, hlo.y);
            hlo.z = fmaf(g, lo.z, hlo.z); hlo.w = fmaf(g, lo.w, hlo.w);
            hhi.x = fmaf(g, hi.x, hhi.x); hhi.y = fmaf(g, hi.y, hhi.y);
            hhi.z = fmaf(g, hi.z, hhi.z); hhi.w = fmaf(g, hi.w, hhi.w);
        }
        // tail rows > 56: re-read from global (L2-hot from the sum tail), rare
        for (int i = s + NROW + rg; i < e; i += 4) {
            const float4 lo = x4[(size_t)i * 32 + (c16 << 1)];
            const float4 hi = x4[(size_t)i * 32 + (c16 << 1) + 1];
            float d = dot8(lo, hi, clo, chi);
            d = row16_sum(d);
            const float g = fast_sigmoid(d);
            hlo.x = fmaf(g, lo.x, hlo.x); hlo.y = fmaf(g, lo.y, hlo.y);
            hlo.z = fmaf(g, lo.z, hlo.z); hlo.w = fmaf(g, lo.w, hlo.w);
            hhi.x = fmaf(g, hi.x, hhi.x); hhi.y = fmaf(g, hi.y, hhi.y);
            hhi.z = fmaf(g, hi.z, hhi.z); hhi.w = fmaf(g, hi.w, hhi.w);
        }
        hlo = f4add(hlo, f4shfl_xor(hlo, 16));
        hlo = f4add(hlo, f4shfl_xor(hlo, 32));
        hhi = f4add(hhi, f4shfl_xor(hhi, 16));
        hhi = f4add(hhi, f4shfl_xor(hhi, 32));
        if (lane < 16) {
            ((float4*)out)[(size_t)b * 32 + (c16 << 1)]     = hlo;
            ((float4*)out)[(size_t)b * 32 + (c16 << 1) + 1] = hhi;
        }
    }
#undef ISSUE
}

extern "C" void kernel_launch(void* const* d_in, const int* in_sizes, int n_in,
                              void* d_out, int out_size, void* d_ws, size_t ws_size,
                              hipStream_t stream) {
    const float* x     = (const float*)d_in[0];
    const float* W     = (const float*)d_in[1];
    const int*   batch = (const int*)d_in[2];
    float*       out   = (float*)d_out;

    const int N = in_sizes[0] / C;   // 2,000,000
    const int B = out_size / C;      // 50,000

    const int grid       = 512;                 // 2 blocks/CU (37 KB LDS each), 8 waves/CU
    const int totalWaves = grid * WPB;          // 2048 waves, ~24 contiguous segments each
    hipLaunchKernelGGL(cba_pipe14_kernel, dim3(grid), dim3(BLK), 0, stream,
                       x, W, batch, out, N, B, totalWaves);
}

// Round 12
// 246.628 us; speedup vs baseline: 1.5560x; 1.5560x over previous
//
#include <hip/hip_runtime.h>
#include <math.h>

#define C        128
#define BLK      256
#define WPB      (BLK / 64)      // 4 waves per block
#define MAXSLOT  12              // 12 slots x 4 row-groups = 48 rows staged / segment
#define NROW     (4 * MAXSLOT)   // 48
#define WSTRIDE  68              // u32 per padded bf16 W row

__device__ __forceinline__ float4 f4add(float4 a, float4 b) {
    float4 r; r.x = a.x + b.x; r.y = a.y + b.y; r.z = a.z + b.z; r.w = a.w + b.w; return r;
}
__device__ __forceinline__ float4 f4shfl_xor(float4 v, int m) {
    float4 r;
    r.x = __shfl_xor(v.x, m, 64);
    r.y = __shfl_xor(v.y, m, 64);
    r.z = __shfl_xor(v.z, m, 64);
    r.w = __shfl_xor(v.w, m, 64);
    return r;
}
__device__ __forceinline__ float4 f4mask(float4 v, bool keep) {
    v.x = keep ? v.x : 0.f; v.y = keep ? v.y : 0.f;
    v.z = keep ? v.z : 0.f; v.w = keep ? v.w : 0.f;
    return v;
}
__device__ __forceinline__ float fast_tanh(float v) {
    const float t = __expf(2.0f * v);
    return 1.0f - 2.0f / (t + 1.0f);
}
__device__ __forceinline__ float fast_sigmoid(float v) {
    return 1.0f / (1.0f + __expf(-v));
}
// RNE-pack two fp32 into one u32 of bf16 (a -> low16, b -> high16)
__device__ __forceinline__ uint32_t pack2(float a, float b) {
    uint32_t ua = __float_as_uint(a), ub = __float_as_uint(b);
    ua = (ua + 0x7FFFu + ((ua >> 16) & 1u)) >> 16;
    ub = (ub + 0x7FFFu + ((ub >> 16) & 1u)) & 0xFFFF0000u;
    return ua | ub;
}
__device__ __forceinline__ float4 unpack4(uint32_t a, uint32_t b) {
    float4 v;
    v.x = __uint_as_float(a << 16);
    v.y = __uint_as_float(a & 0xFFFF0000u);
    v.z = __uint_as_float(b << 16);
    v.w = __uint_as_float(b & 0xFFFF0000u);
    return v;
}
// sum across the 16 lanes of this row-group; pure VALU (DPP row_ror tree)
__device__ __forceinline__ float row16_sum(float d) {
    d += __int_as_float(__builtin_amdgcn_update_dpp(0, __float_as_int(d), 0x128, 0xF, 0xF, true));
    d += __int_as_float(__builtin_amdgcn_update_dpp(0, __float_as_int(d), 0x124, 0xF, 0xF, true));
    d += __int_as_float(__builtin_amdgcn_update_dpp(0, __float_as_int(d), 0x122, 0xF, 0xF, true));
    d += __int_as_float(__builtin_amdgcn_update_dpp(0, __float_as_int(d), 0x121, 0xF, 0xF, true));
    return d;
}
__device__ __forceinline__ float dot8(float4 lo, float4 hi, float4 clo, float4 chi) {
    float a = lo.x * clo.x + lo.y * clo.y;
    float b = lo.z * clo.z + lo.w * clo.w;
    float c = hi.x * chi.x + hi.y * chi.y;
    float d = hi.z * chi.z + hi.w * chi.w;
    return (a + b) + (c + d);
}

extern "C" __global__ __launch_bounds__(BLK)
__attribute__((amdgpu_waves_per_eu(2, 2)))   // PIN 2 waves/EU: 256-VGPR budget (round-9 proven)
void cba_dense_kernel(const float* __restrict__ x,
                      const float* __restrict__ W,
                      const int* __restrict__ batch,
                      float* __restrict__ out,
                      int N, int B, int totalWaves)
{
    // W bf16, padded rows of 64 u32 in two 32-u32 halves; each half rotated by
    // 8*(k>>5) so the 4 row-groups (reading k-quarters 32 apart) hit disjoint banks.
    __shared__ uint32_t sWb[C * WSTRIDE];   // 34816 B
    __shared__ float4   sMean[WPB * 32];    // 2048 B : per-wave mean broadcast

    const int t    = threadIdx.x;
    const int lane = t & 63;
    const int wid  = t >> 6;       // wave in block 0..3
    const int rg   = lane >> 4;    // row-group / split-K quarter 0..3
    const int c16  = lane & 15;    // owns cols 4*c16..+3 (lo) and 64+4*c16..+3 (hi)

    // ---- one-time: W -> bf16 -> LDS (half-rotated) ----
    const float2* W2 = (const float2*)W;
    for (int p = t; p < C * 64; p += BLK) {
        const int k = p >> 6, j = p & 63;
        const int rot = (k >> 5) << 3;                 // 8 * quarter
        const int pos = (j < 32) ? ((j + rot) & 31)
                                 : (32 + ((j - 32 + rot) & 31));
        const float2 wv = W2[p];                       // W[k][2j], W[k][2j+1]
        sWb[k * WSTRIDE + pos] = pack2(wv.x, wv.y);
    }
    __syncthreads();

    const int gw = blockIdx.x * WPB + wid;

    // ---- chunk-contiguous segment assignment ----
    const int qn = B / totalWaves;
    const int r  = B % totalWaves;
    const int segStart = gw * qn + (gw < r ? gw : r);
    const int myCnt    = qn + (gw < r ? 1 : 0);       // <= 25

    // ---- lane-parallel boundary search ----
    const int tl     = lane < myCnt ? lane : myCnt;
    const int target = segStart + tl;
    int lo_ = 0, hi_ = N;
    while (lo_ < hi_) {
        int mid = (lo_ + hi_) >> 1;
        if (batch[mid] < target) lo_ = mid + 1; else hi_ = mid;
    }
    const int bs = lo_;

    const float4* x4  = (const float4*)x;
    const int     Nm1 = N - 1;
    float4* mb = sMean + wid * 32;
    const int wco = (2 * c16 + (rg << 3)) & 31;       // rotated u32 offset within a W half

    // prefetch window: next segment's rows, fp32 (96 VGPR). DENSE loads:
    // lo = float4 at row*512B + c16*16B   (16 lanes cover bytes [0,256) of the row)
    // hi = float4 at row*512B + 256 + c16*16B (bytes [256,512))
    float4 pl[MAXSLOT], ph[MAXSLOT];

#define ISSUE(sseg)                                                    \
    {                                                                  \
        _Pragma("unroll")                                              \
        for (int sl = 0; sl < MAXSLOT; ++sl) {                         \
            const int row = (sseg) + 4 * sl + rg;                      \
            const int rc  = row < Nm1 ? row : Nm1;                     \
            pl[sl] = x4[(size_t)rc * 32 + c16];                        \
            ph[sl] = x4[(size_t)rc * 32 + 16 + c16];                   \
        }                                                              \
    }

    int sCur = 0, eCur = 0;
    if (myCnt > 0) {
        sCur = __shfl(bs, 0, 64);
        eCur = __shfl(bs, 1, 64);
        ISSUE(sCur);                                   // prologue: segment 0 in flight
    }

    for (int k = 0; k < myCnt; ++k) {
        const int b   = segStart + k;
        const int s   = sCur;
        const int e   = eCur;
        const int cnt = e - s;

        // ======== consume prefetched rows: mask, fp32 sum, bf16-pack to regs ========
        uint4 rbPk[MAXSLOT];                           // 48 VGPR: current segment, bf16
        float4 alo = make_float4(0.f,0.f,0.f,0.f), ahi = alo;
#pragma unroll
        for (int sl = 0; sl < MAXSLOT; ++sl) {
            const bool valid = (s + 4 * sl + rg) < e;
            const float4 lo = f4mask(pl[sl], valid);
            const float4 hi = f4mask(ph[sl], valid);
            alo = f4add(alo, lo); ahi = f4add(ahi, hi);
            rbPk[sl].x = pack2(lo.x, lo.y); rbPk[sl].y = pack2(lo.z, lo.w);
            rbPk[sl].z = pack2(hi.x, hi.y); rbPk[sl].w = pack2(hi.z, hi.w);
        }
        // rare tail rows > 48 (9% of segments): sum synchronously
        for (int i = s + NROW + rg; i < e; i += 4) {
            alo = f4add(alo, x4[(size_t)i * 32 + c16]);
            ahi = f4add(ahi, x4[(size_t)i * 32 + 16 + c16]);
        }

        // ======== issue prefetch for segment k+1 NOW; flies under GEMM + pass 2 ========
        if (k + 1 < myCnt) {
            sCur = __shfl(bs, k + 1, 64);
            eCur = __shfl(bs, k + 2, 64);
            ISSUE(sCur);
        }
        __builtin_amdgcn_sched_barrier(0);             // keep the loads above the compute

        // ======== mean (cross-row-group reduce) ========
        alo = f4add(alo, f4shfl_xor(alo, 16));
        alo = f4add(alo, f4shfl_xor(alo, 32));
        ahi = f4add(ahi, f4shfl_xor(ahi, 16));
        ahi = f4add(ahi, f4shfl_xor(ahi, 32));
        const float inv = 1.0f / (float)(cnt > 0 ? cnt : 1);
        if (lane < 16) {
            float4 mlo, mhi;
            mlo.x = alo.x*inv; mlo.y = alo.y*inv; mlo.z = alo.z*inv; mlo.w = alo.w*inv;
            mhi.x = ahi.x*inv; mhi.y = ahi.y*inv; mhi.z = ahi.z*inv; mhi.w = ahi.w*inv;
            mb[c16]      = mlo;                        // mb[i] = mean cols 4i..4i+3
            mb[16 + c16] = mhi;
        }
        // same-wave ds_write -> ds_read; compiler inserts lgkmcnt

        // ======== GEMM: c = tanh(mean @ W); quarter rg covers k in [32rg, 32rg+32) ========
        float4 plo = make_float4(0.f,0.f,0.f,0.f), phi = plo;
#pragma unroll
        for (int jq = 0; jq < 8; ++jq) {
            const float4 m4 = mb[(rg << 3) + jq];      // mean[k0..k0+3]
            const int kb = (rg << 5) + (jq << 2);
#define FMAK(mm, kk)                                                           \
            {                                                                  \
                const uint32_t* rowp = &sWb[(kk) * WSTRIDE];                   \
                const uint2 ul = *(const uint2*)&rowp[wco];                    \
                const uint2 uh = *(const uint2*)&rowp[32 + wco];               \
                plo.x = fmaf(mm, __uint_as_float(ul.x << 16),         plo.x);  \
                plo.y = fmaf(mm, __uint_as_float(ul.x & 0xFFFF0000u), plo.y);  \
                plo.z = fmaf(mm, __uint_as_float(ul.y << 16),         plo.z);  \
                plo.w = fmaf(mm, __uint_as_float(ul.y & 0xFFFF0000u), plo.w);  \
                phi.x = fmaf(mm, __uint_as_float(uh.x << 16),         phi.x);  \
                phi.y = fmaf(mm, __uint_as_float(uh.x & 0xFFFF0000u), phi.y);  \
                phi.z = fmaf(mm, __uint_as_float(uh.y << 16),         phi.z);  \
                phi.w = fmaf(mm, __uint_as_float(uh.y & 0xFFFF0000u), phi.w);  \
            }
            FMAK(m4.x, kb + 0); FMAK(m4.y, kb + 1);
            FMAK(m4.z, kb + 2); FMAK(m4.w, kb + 3);
#undef FMAK
        }
        plo = f4add(plo, f4shfl_xor(plo, 16));
        plo = f4add(plo, f4shfl_xor(plo, 32));
        phi = f4add(phi, f4shfl_xor(phi, 16));
        phi = f4add(phi, f4shfl_xor(phi, 32));
        float4 clo, chi;
        clo.x = fast_tanh(plo.x); clo.y = fast_tanh(plo.y);
        clo.z = fast_tanh(plo.z); clo.w = fast_tanh(plo.w);
        chi.x = fast_tanh(phi.x); chi.y = fast_tanh(phi.y);
        chi.z = fast_tanh(phi.z); chi.w = fast_tanh(phi.w);

        // ======== pass 2: gates + h from bf16 regs; DPP-only row reduction ========
        float4 hlo = make_float4(0.f,0.f,0.f,0.f), hhi = hlo;
#pragma unroll
        for (int sl = 0; sl < MAXSLOT; ++sl) {
            const float4 lo = unpack4(rbPk[sl].x, rbPk[sl].y);
            const float4 hi = unpack4(rbPk[sl].z, rbPk[sl].w);
            float d = dot8(lo, hi, clo, chi);
            d = row16_sum(d);
            const float g = fast_sigmoid(d);           // masked rows staged as 0 -> g*0
            hlo.x = fmaf(g, lo.x, hlo.x); hlo.y = fmaf(g, lo.y, hlo.y);
            hlo.z = fmaf(g, lo.z, hlo.z); hlo.w = fmaf(g, lo.w, hlo.w);
            hhi.x = fmaf(g, hi.x, hhi.x); hhi.y = fmaf(g, hi.y, hhi.y);
            hhi.z = fmaf(g, hi.z, hhi.z); hhi.w = fmaf(g, hi.w, hhi.w);
        }
        // tail rows > 48: re-read from global (L2-hot from the sum tail), rare
        for (int i = s + NROW + rg; i < e; i += 4) {
            const float4 lo = x4[(size_t)i * 32 + c16];
            const float4 hi = x4[(size_t)i * 32 + 16 + c16];
            float d = dot8(lo, hi, clo, chi);
            d = row16_sum(d);
            const float g = fast_sigmoid(d);
            hlo.x = fmaf(g, lo.x, hlo.x); hlo.y = fmaf(g, lo.y, hlo.y);
            hlo.z = fmaf(g, lo.z, hlo.z); hlo.w = fmaf(g, lo.w, hlo.w);
            hhi.x = fmaf(g, hi.x, hhi.x); hhi.y = fmaf(g, hi.y, hhi.y);
            hhi.z = fmaf(g, hi.z, hhi.z); hhi.w = fmaf(g, hi.w, hhi.w);
        }
        hlo = f4add(hlo, f4shfl_xor(hlo, 16));
        hlo = f4add(hlo, f4shfl_xor(hlo, 32));
        hhi = f4add(hhi, f4shfl_xor(hhi, 16));
        hhi = f4add(hhi, f4shfl_xor(hhi, 32));
        if (lane < 16) {
            ((float4*)out)[(size_t)b * 32 + c16]      = hlo;   // cols 4c16..+3
            ((float4*)out)[(size_t)b * 32 + 16 + c16] = hhi;   // cols 64+4c16..+3
        }
    }
#undef ISSUE
}

extern "C" void kernel_launch(void* const* d_in, const int* in_sizes, int n_in,
                              void* d_out, int out_size, void* d_ws, size_t ws_size,
                              hipStream_t stream) {
    const float* x     = (const float*)d_in[0];
    const float* W     = (const float*)d_in[1];
    const int*   batch = (const int*)d_in[2];
    float*       out   = (float*)d_out;

    const int N = in_sizes[0] / C;   // 2,000,000
    const int B = out_size / C;      // 50,000

    const int grid       = 512;                 // 2 blocks/CU (37 KB LDS each), 8 waves/CU
    const int totalWaves = grid * WPB;          // 2048 waves, ~24 contiguous segments each
    hipLaunchKernelGGL(cba_dense_kernel, dim3(grid), dim3(BLK), 0, stream,
                       x, W, batch, out, N, B, totalWaves);
}

// Round 13
// 243.294 us; speedup vs baseline: 1.5774x; 1.0137x over previous
//
#include <hip/hip_runtime.h>
#include <math.h>

#define C        128
#define BLK      256
#define WPB      (BLK / 64)      // 4 waves per block
#define MAXSLOT  12              // 12 slots x 4 row-groups = 48 rows staged / segment
#define NROW     (4 * MAXSLOT)   // 48
#define WSTRIDE  68              // u32 per padded bf16 W row

__device__ __forceinline__ float4 f4add(float4 a, float4 b) {
    float4 r; r.x = a.x + b.x; r.y = a.y + b.y; r.z = a.z + b.z; r.w = a.w + b.w; return r;
}
__device__ __forceinline__ float4 f4shfl_xor(float4 v, int m) {
    float4 r;
    r.x = __shfl_xor(v.x, m, 64);
    r.y = __shfl_xor(v.y, m, 64);
    r.z = __shfl_xor(v.z, m, 64);
    r.w = __shfl_xor(v.w, m, 64);
    return r;
}
__device__ __forceinline__ float4 f4mask(float4 v, bool keep) {
    v.x = keep ? v.x : 0.f; v.y = keep ? v.y : 0.f;
    v.z = keep ? v.z : 0.f; v.w = keep ? v.w : 0.f;
    return v;
}
__device__ __forceinline__ float fast_tanh(float v) {
    const float t = __expf(2.0f * v);
    return 1.0f - 2.0f / (t + 1.0f);
}
__device__ __forceinline__ float fast_sigmoid(float v) {
    return 1.0f / (1.0f + __expf(-v));
}
// RNE-pack two fp32 into one u32 of bf16 (a -> low16, b -> high16)
__device__ __forceinline__ uint32_t pack2(float a, float b) {
    uint32_t ua = __float_as_uint(a), ub = __float_as_uint(b);
    ua = (ua + 0x7FFFu + ((ua >> 16) & 1u)) >> 16;
    ub = (ub + 0x7FFFu + ((ub >> 16) & 1u)) & 0xFFFF0000u;
    return ua | ub;
}
__device__ __forceinline__ float4 unpack4(uint32_t a, uint32_t b) {
    float4 v;
    v.x = __uint_as_float(a << 16);
    v.y = __uint_as_float(a & 0xFFFF0000u);
    v.z = __uint_as_float(b << 16);
    v.w = __uint_as_float(b & 0xFFFF0000u);
    return v;
}
// sum across the 16 lanes of this row-group; pure VALU (DPP row_ror tree)
__device__ __forceinline__ float row16_sum(float d) {
    d += __int_as_float(__builtin_amdgcn_update_dpp(0, __float_as_int(d), 0x128, 0xF, 0xF, true));
    d += __int_as_float(__builtin_amdgcn_update_dpp(0, __float_as_int(d), 0x124, 0xF, 0xF, true));
    d += __int_as_float(__builtin_amdgcn_update_dpp(0, __float_as_int(d), 0x122, 0xF, 0xF, true));
    d += __int_as_float(__builtin_amdgcn_update_dpp(0, __float_as_int(d), 0x121, 0xF, 0xF, true));
    return d;
}
__device__ __forceinline__ float dot8(float4 lo, float4 hi, float4 clo, float4 chi) {
    float a = lo.x * clo.x + lo.y * clo.y;
    float b = lo.z * clo.z + lo.w * clo.w;
    float c = hi.x * chi.x + hi.y * chi.y;
    float d = hi.z * chi.z + hi.w * chi.w;
    return (a + b) + (c + d);
}

extern "C" __global__ __launch_bounds__(BLK)
__attribute__((amdgpu_waves_per_eu(2, 2)))   // PIN 2 waves/EU: 256-VGPR budget (round-9/12 proven)
void cba_dense2_kernel(const float* __restrict__ x,
                       const float* __restrict__ W,
                       const int* __restrict__ batch,
                       float* __restrict__ out,
                       int N, int B, int totalWaves)
{
    // W bf16, padded rows of 64 u32 in two 32-u32 halves; each half rotated by
    // 8*(k>>5) so the 4 row-groups (reading k-quarters 32 apart) hit disjoint banks.
    __shared__ uint32_t sWb[C * WSTRIDE];   // 34816 B
    __shared__ float4   sMean[WPB * 32];    // 2048 B : per-wave mean broadcast

    const int t    = threadIdx.x;
    const int lane = t & 63;
    const int wid  = t >> 6;       // wave in block 0..3
    const int rg   = lane >> 4;    // row-group / split-K quarter 0..3
    const int c16  = lane & 15;    // owns cols 4*c16..+3 (lo) and 64+4*c16..+3 (hi)

    // ---- one-time: W -> bf16 -> LDS (half-rotated) ----
    const float2* W2 = (const float2*)W;
    for (int p = t; p < C * 64; p += BLK) {
        const int k = p >> 6, j = p & 63;
        const int rot = (k >> 5) << 3;                 // 8 * quarter
        const int pos = (j < 32) ? ((j + rot) & 31)
                                 : (32 + ((j - 32 + rot) & 31));
        const float2 wv = W2[p];                       // W[k][2j], W[k][2j+1]
        sWb[k * WSTRIDE + pos] = pack2(wv.x, wv.y);
    }
    __syncthreads();

    const int gw = blockIdx.x * WPB + wid;

    // ---- chunk-contiguous segment assignment ----
    const int qn = B / totalWaves;
    const int r  = B % totalWaves;
    const int segStart = gw * qn + (gw < r ? gw : r);
    const int myCnt    = qn + (gw < r ? 1 : 0);       // <= 25

    // ---- lane-parallel boundary search ----
    const int tl     = lane < myCnt ? lane : myCnt;
    const int target = segStart + tl;
    int lo_ = 0, hi_ = N;
    while (lo_ < hi_) {
        int mid = (lo_ + hi_) >> 1;
        if (batch[mid] < target) lo_ = mid + 1; else hi_ = mid;
    }
    const int bs = lo_;

    const float4* x4  = (const float4*)x;
    const int     Nm1 = N - 1;
    float4* mb = sMean + wid * 32;
    const int wco = (2 * c16 + (rg << 3)) & 31;       // rotated u32 offset within a W half

    // prefetch window: next segment's rows, fp32 (96 VGPR). DENSE loads.
    float4 pl[MAXSLOT], ph[MAXSLOT];

    // Invalid slots (row >= eseg) clamp to the segment's LAST VALID row, so they
    // hit a line a valid slot already fetched (L1/L2-hit) instead of pulling
    // next-segment lines that may be L2-evicted before reuse (HBM double-fetch).
#define ISSUE(sseg, eseg)                                              \
    {                                                                  \
        int lastv = (eseg) - 1;                                        \
        lastv = lastv > (sseg) ? lastv : (sseg);                       \
        lastv = lastv < Nm1 ? lastv : Nm1;                             \
        _Pragma("unroll")                                              \
        for (int sl = 0; sl < MAXSLOT; ++sl) {                         \
            const int row = (sseg) + 4 * sl + rg;                      \
            const int rc  = row < (eseg) ? row : lastv;                \
            pl[sl] = x4[(size_t)rc * 32 + c16];                        \
            ph[sl] = x4[(size_t)rc * 32 + 16 + c16];                   \
        }                                                              \
    }

    int sCur = 0, eCur = 0;
    if (myCnt > 0) {
        sCur = __shfl(bs, 0, 64);
        eCur = __shfl(bs, 1, 64);
        ISSUE(sCur, eCur);                             // prologue: segment 0 in flight
    }

    for (int k = 0; k < myCnt; ++k) {
        const int b   = segStart + k;
        const int s   = sCur;
        const int e   = eCur;
        const int cnt = e - s;

        // ======== consume prefetched rows: mask, fp32 sum, bf16-pack to regs ========
        uint4 rbPk[MAXSLOT];                           // 48 VGPR: current segment, bf16
        float4 alo = make_float4(0.f,0.f,0.f,0.f), ahi = alo;
#pragma unroll
        for (int sl = 0; sl < MAXSLOT; ++sl) {
            const bool valid = (s + 4 * sl + rg) < e;
            const float4 lo = f4mask(pl[sl], valid);
            const float4 hi = f4mask(ph[sl], valid);
            alo = f4add(alo, lo); ahi = f4add(ahi, hi);
            rbPk[sl].x = pack2(lo.x, lo.y); rbPk[sl].y = pack2(lo.z, lo.w);
            rbPk[sl].z = pack2(hi.x, hi.y); rbPk[sl].w = pack2(hi.z, hi.w);
        }
        // rare tail rows > 48 (9% of segments): sum synchronously
        for (int i = s + NROW + rg; i < e; i += 4) {
            alo = f4add(alo, x4[(size_t)i * 32 + c16]);
            ahi = f4add(ahi, x4[(size_t)i * 32 + 16 + c16]);
        }

        // ======== issue prefetch for segment k+1 NOW; flies under GEMM + pass 2 ========
        if (k + 1 < myCnt) {
            sCur = __shfl(bs, k + 1, 64);
            eCur = __shfl(bs, k + 2, 64);
            ISSUE(sCur, eCur);
        }
        __builtin_amdgcn_sched_barrier(0);             // keep the loads above the compute

        // ======== mean (cross-row-group reduce) ========
        alo = f4add(alo, f4shfl_xor(alo, 16));
        alo = f4add(alo, f4shfl_xor(alo, 32));
        ahi = f4add(ahi, f4shfl_xor(ahi, 16));
        ahi = f4add(ahi, f4shfl_xor(ahi, 32));
        const float inv = 1.0f / (float)(cnt > 0 ? cnt : 1);
        if (lane < 16) {
            float4 mlo, mhi;
            mlo.x = alo.x*inv; mlo.y = alo.y*inv; mlo.z = alo.z*inv; mlo.w = alo.w*inv;
            mhi.x = ahi.x*inv; mhi.y = ahi.y*inv; mhi.z = ahi.z*inv; mhi.w = ahi.w*inv;
            mb[c16]      = mlo;                        // mb[i] = mean cols 4i..4i+3
            mb[16 + c16] = mhi;
        }
        // same-wave ds_write -> ds_read; compiler inserts lgkmcnt

        // ======== GEMM: c = tanh(mean @ W); quarter rg covers k in [32rg, 32rg+32) ========
        float4 plo = make_float4(0.f,0.f,0.f,0.f), phi = plo;
#pragma unroll
        for (int jq = 0; jq < 8; ++jq) {
            const float4 m4 = mb[(rg << 3) + jq];      // mean[k0..k0+3]
            const int kb = (rg << 5) + (jq << 2);
#define FMAK(mm, kk)                                                           \
            {                                                                  \
                const uint32_t* rowp = &sWb[(kk) * WSTRIDE];                   \
                const uint2 ul = *(const uint2*)&rowp[wco];                    \
                const uint2 uh = *(const uint2*)&rowp[32 + wco];               \
                plo.x = fmaf(mm, __uint_as_float(ul.x << 16),         plo.x);  \
                plo.y = fmaf(mm, __uint_as_float(ul.x & 0xFFFF0000u), plo.y);  \
                plo.z = fmaf(mm, __uint_as_float(ul.y << 16),         plo.z);  \
                plo.w = fmaf(mm, __uint_as_float(ul.y & 0xFFFF0000u), plo.w);  \
                phi.x = fmaf(mm, __uint_as_float(uh.x << 16),         phi.x);  \
                phi.y = fmaf(mm, __uint_as_float(uh.x & 0xFFFF0000u), phi.y);  \
                phi.z = fmaf(mm, __uint_as_float(uh.y << 16),         phi.z);  \
                phi.w = fmaf(mm, __uint_as_float(uh.y & 0xFFFF0000u), phi.w);  \
            }
            FMAK(m4.x, kb + 0); FMAK(m4.y, kb + 1);
            FMAK(m4.z, kb + 2); FMAK(m4.w, kb + 3);
#undef FMAK
        }
        plo = f4add(plo, f4shfl_xor(plo, 16));
        plo = f4add(plo, f4shfl_xor(plo, 32));
        phi = f4add(phi, f4shfl_xor(phi, 16));
        phi = f4add(phi, f4shfl_xor(phi, 32));
        float4 clo, chi;
        clo.x = fast_tanh(plo.x); clo.y = fast_tanh(plo.y);
        clo.z = fast_tanh(plo.z); clo.w = fast_tanh(plo.w);
        chi.x = fast_tanh(phi.x); chi.y = fast_tanh(phi.y);
        chi.z = fast_tanh(phi.z); chi.w = fast_tanh(phi.w);

        // ======== pass 2: gates + h from bf16 regs; DPP-only row reduction ========
        float4 hlo = make_float4(0.f,0.f,0.f,0.f), hhi = hlo;
#pragma unroll
        for (int sl = 0; sl < MAXSLOT; ++sl) {
            const float4 lo = unpack4(rbPk[sl].x, rbPk[sl].y);
            const float4 hi = unpack4(rbPk[sl].z, rbPk[sl].w);
            float d = dot8(lo, hi, clo, chi);
            d = row16_sum(d);
            const float g = fast_sigmoid(d);           // masked rows staged as 0 -> g*0
            hlo.x = fmaf(g, lo.x, hlo.x); hlo.y = fmaf(g, lo.y, hlo.y);
            hlo.z = fmaf(g, lo.z, hlo.z); hlo.w = fmaf(g, lo.w, hlo.w);
            hhi.x = fmaf(g, hi.x, hhi.x); hhi.y = fmaf(g, hi.y, hhi.y);
            hhi.z = fmaf(g, hi.z, hhi.z); hhi.w = fmaf(g, hi.w, hhi.w);
        }
        // tail rows > 48: re-read from global (L2-hot from the sum tail), rare
        for (int i = s + NROW + rg; i < e; i += 4) {
            const float4 lo = x4[(size_t)i * 32 + c16];
            const float4 hi = x4[(size_t)i * 32 + 16 + c16];
            float d = dot8(lo, hi, clo, chi);
            d = row16_sum(d);
            const float g = fast_sigmoid(d);
            hlo.x = fmaf(g, lo.x, hlo.x); hlo.y = fmaf(g, lo.y, hlo.y);
            hlo.z = fmaf(g, lo.z, hlo.z); hlo.w = fmaf(g, lo.w, hlo.w);
            hhi.x = fmaf(g, hi.x, hhi.x); hhi.y = fmaf(g, hi.y, hhi.y);
            hhi.z = fmaf(g, hi.z, hhi.z); hhi.w = fmaf(g, hi.w, hhi.w);
        }
        hlo = f4add(hlo, f4shfl_xor(hlo, 16));
        hlo = f4add(hlo, f4shfl_xor(hlo, 32));
        hhi = f4add(hhi, f4shfl_xor(hhi, 16));
        hhi = f4add(hhi, f4shfl_xor(hhi, 32));
        if (lane < 16) {
            ((float4*)out)[(size_t)b * 32 + c16]      = hlo;   // cols 4c16..+3
            ((float4*)out)[(size_t)b * 32 + 16 + c16] = hhi;   // cols 64+4c16..+3
        }
    }
#undef ISSUE
}

extern "C" void kernel_launch(void* const* d_in, const int* in_sizes, int n_in,
                              void* d_out, int out_size, void* d_ws, size_t ws_size,
                              hipStream_t stream) {
    const float* x     = (const float*)d_in[0];
    const float* W     = (const float*)d_in[1];
    const int*   batch = (const int*)d_in[2];
    float*       out   = (float*)d_out;

    const int N = in_sizes[0] / C;   // 2,000,000
    const int B = out_size / C;      // 50,000

    const int grid       = 512;                 // 2 blocks/CU (37 KB LDS each), 8 waves/CU
    const int totalWaves = grid * WPB;          // 2048 waves, ~24 contiguous segments each
    hipLaunchKernelGGL(cba_dense2_kernel, dim3(grid), dim3(BLK), 0, stream,
                       x, W, batch, out, N, B, totalWaves);
}

// Round 14
// 241.714 us; speedup vs baseline: 1.5877x; 1.0065x over previous
//
#include <hip/hip_runtime.h>
#include <math.h>

#define C        128
#define BLK      256
#define WPB      (BLK / 64)      // 4 waves per block
#define MAXSLOT  12              // 12 slots x 4 row-groups = 48 rows staged / segment
#define NROW     (4 * MAXSLOT)   // 48
#define WSTRIDE  68              // u32 per padded bf16 W row

__device__ __forceinline__ float4 f4add(float4 a, float4 b) {
    float4 r; r.x = a.x + b.x; r.y = a.y + b.y; r.z = a.z + b.z; r.w = a.w + b.w; return r;
}
__device__ __forceinline__ float4 f4shfl_xor(float4 v, int m) {
    float4 r;
    r.x = __shfl_xor(v.x, m, 64);
    r.y = __shfl_xor(v.y, m, 64);
    r.z = __shfl_xor(v.z, m, 64);
    r.w = __shfl_xor(v.w, m, 64);
    return r;
}
__device__ __forceinline__ float4 f4mask(float4 v, bool keep) {
    v.x = keep ? v.x : 0.f; v.y = keep ? v.y : 0.f;
    v.z = keep ? v.z : 0.f; v.w = keep ? v.w : 0.f;
    return v;
}
__device__ __forceinline__ float fast_tanh(float v) {
    const float t = __expf(2.0f * v);
    return 1.0f - 2.0f / (t + 1.0f);
}
__device__ __forceinline__ float fast_sigmoid(float v) {
    return 1.0f / (1.0f + __expf(-v));
}
// RNE-pack two fp32 into one u32 of bf16 (a -> low16, b -> high16)
__device__ __forceinline__ uint32_t pack2(float a, float b) {
    uint32_t ua = __float_as_uint(a), ub = __float_as_uint(b);
    ua = (ua + 0x7FFFu + ((ua >> 16) & 1u)) >> 16;
    ub = (ub + 0x7FFFu + ((ub >> 16) & 1u)) & 0xFFFF0000u;
    return ua | ub;
}
__device__ __forceinline__ float4 unpack4(uint32_t a, uint32_t b) {
    float4 v;
    v.x = __uint_as_float(a << 16);
    v.y = __uint_as_float(a & 0xFFFF0000u);
    v.z = __uint_as_float(b << 16);
    v.w = __uint_as_float(b & 0xFFFF0000u);
    return v;
}
// sum across the 16 lanes of this row-group; pure VALU (DPP row_ror tree)
__device__ __forceinline__ float row16_sum(float d) {
    d += __int_as_float(__builtin_amdgcn_update_dpp(0, __float_as_int(d), 0x128, 0xF, 0xF, true));
    d += __int_as_float(__builtin_amdgcn_update_dpp(0, __float_as_int(d), 0x124, 0xF, 0xF, true));
    d += __int_as_float(__builtin_amdgcn_update_dpp(0, __float_as_int(d), 0x122, 0xF, 0xF, true));
    d += __int_as_float(__builtin_amdgcn_update_dpp(0, __float_as_int(d), 0x121, 0xF, 0xF, true));
    return d;
}
__device__ __forceinline__ float dot8(float4 lo, float4 hi, float4 clo, float4 chi) {
    float a = lo.x * clo.x + lo.y * clo.y;
    float b = lo.z * clo.z + lo.w * clo.w;
    float c = hi.x * chi.x + hi.y * chi.y;
    float d = hi.z * chi.z + hi.w * chi.w;
    return (a + b) + (c + d);
}

extern "C" __global__ __launch_bounds__(BLK)
__attribute__((amdgpu_waves_per_eu(2, 2)))   // PIN 2 waves/EU: 256-VGPR budget (round-9/12 proven)
void cba_blkloc_kernel(const float* __restrict__ x,
                       const float* __restrict__ W,
                       const int* __restrict__ batch,
                       float* __restrict__ out,
                       int N, int B, int nBlocks)
{
    __shared__ uint32_t sWb[C * WSTRIDE];   // 34816 B : bf16 W, half-rotated padded rows
    __shared__ float4   sMean[WPB * 32];    // 2048 B  : per-wave mean broadcast

    const int t    = threadIdx.x;
    const int lane = t & 63;
    const int wid  = t >> 6;       // wave in block 0..3
    const int rg   = lane >> 4;    // row-group / split-K quarter 0..3
    const int c16  = lane & 15;    // owns cols 4*c16..+3 (lo) and 64+4*c16..+3 (hi)

    // ---- one-time: W -> bf16 -> LDS (half-rotated) ----
    const float2* W2 = (const float2*)W;
    for (int p = t; p < C * 64; p += BLK) {
        const int k = p >> 6, j = p & 63;
        const int rot = (k >> 5) << 3;                 // 8 * quarter
        const int pos = (j < 32) ? ((j + rot) & 31)
                                 : (32 + ((j - 32 + rot) & 31));
        const float2 wv = W2[p];
        sWb[k * WSTRIDE + pos] = pack2(wv.x, wv.y);
    }
    __syncthreads();

    // ---- BLOCK owns a contiguous run of segments; its 4 waves round-robin them.
    //      At any instant the block's 4 waves stream one contiguous x region. ----
    const int bid = blockIdx.x;
    const int qb  = B / nBlocks;
    const int rb  = B % nBlocks;
    const int blockStart = bid * qb + (bid < rb ? bid : rb);
    const int blkCnt     = qb + (bid < rb ? 1 : 0);    // ~97-98
    const int myCnt      = (blkCnt > wid) ? ((blkCnt - wid + 3) >> 2) : 0;   // <= 25

    // ---- per-wave two-sided boundary search:
    //      lane l (<32):  start of segment blockStart + 4l + wid
    //      lane 32+l:     start of segment blockStart + 4l + wid + 1 (its end) ----
    {
        const int l   = lane & 31;
        int tgt = blockStart + 4 * l + wid + ((lane >> 5) & 1);
        tgt = tgt < B ? tgt : B;
        int lo_ = 0, hi_ = N;
        while (lo_ < hi_) {
            int mid = (lo_ + hi_) >> 1;
            if (batch[mid] < tgt) lo_ = mid + 1; else hi_ = mid;
        }
        const int bs = lo_;

        const float4* x4  = (const float4*)x;
        const int     Nm1 = N - 1;
        float4* mb = sMean + wid * 32;
        const int wco = (2 * c16 + (rg << 3)) & 31;    // rotated u32 offset within a W half

        float4 pl[MAXSLOT], ph[MAXSLOT];               // prefetch window (96 VGPR)

#define ISSUE(sseg, eseg)                                              \
        {                                                              \
            int lastv = (eseg) - 1;                                    \
            lastv = lastv > (sseg) ? lastv : (sseg);                   \
            lastv = lastv < Nm1 ? lastv : Nm1;                         \
            _Pragma("unroll")                                          \
            for (int sl = 0; sl < MAXSLOT; ++sl) {                     \
                const int row = (sseg) + 4 * sl + rg;                  \
                const int rc  = row < (eseg) ? row : lastv;            \
                pl[sl] = x4[(size_t)rc * 32 + c16];                    \
                ph[sl] = x4[(size_t)rc * 32 + 16 + c16];               \
            }                                                          \
        }

        int sCur = 0, eCur = 0;
        if (myCnt > 0) {
            sCur = __shfl(bs, 0, 64);
            eCur = __shfl(bs, 32, 64);
            ISSUE(sCur, eCur);                         // prologue: first segment in flight
        }

        for (int k = 0; k < myCnt; ++k) {
            const int b   = blockStart + 4 * k + wid;
            const int s   = sCur;
            const int e   = eCur;
            const int cnt = e - s;

            // ======== consume prefetched rows: mask, fp32 sum, bf16-pack to regs ========
            uint4 rbPk[MAXSLOT];                       // 48 VGPR
            float4 alo = make_float4(0.f,0.f,0.f,0.f), ahi = alo;
#pragma unroll
            for (int sl = 0; sl < MAXSLOT; ++sl) {
                const bool valid = (s + 4 * sl + rg) < e;
                const float4 lo = f4mask(pl[sl], valid);
                const float4 hi = f4mask(ph[sl], valid);
                alo = f4add(alo, lo); ahi = f4add(ahi, hi);
                rbPk[sl].x = pack2(lo.x, lo.y); rbPk[sl].y = pack2(lo.z, lo.w);
                rbPk[sl].z = pack2(hi.x, hi.y); rbPk[sl].w = pack2(hi.z, hi.w);
            }
            // rare tail rows > 48 (9% of segments): sum synchronously
            for (int i = s + NROW + rg; i < e; i += 4) {
                alo = f4add(alo, x4[(size_t)i * 32 + c16]);
                ahi = f4add(ahi, x4[(size_t)i * 32 + 16 + c16]);
            }

            // ======== issue prefetch for this wave's NEXT segment now ========
            if (k + 1 < myCnt) {
                sCur = __shfl(bs, k + 1, 64);
                eCur = __shfl(bs, 32 + k + 1, 64);
                ISSUE(sCur, eCur);
            }
            __builtin_amdgcn_sched_barrier(0);         // keep the loads above the compute

            // ======== mean (cross-row-group reduce) ========
            alo = f4add(alo, f4shfl_xor(alo, 16));
            alo = f4add(alo, f4shfl_xor(alo, 32));
            ahi = f4add(ahi, f4shfl_xor(ahi, 16));
            ahi = f4add(ahi, f4shfl_xor(ahi, 32));
            const float inv = 1.0f / (float)(cnt > 0 ? cnt : 1);
            if (lane < 16) {
                float4 mlo, mhi;
                mlo.x = alo.x*inv; mlo.y = alo.y*inv; mlo.z = alo.z*inv; mlo.w = alo.w*inv;
                mhi.x = ahi.x*inv; mhi.y = ahi.y*inv; mhi.z = ahi.z*inv; mhi.w = ahi.w*inv;
                mb[c16]      = mlo;                    // mb[i] = mean cols 4i..4i+3
                mb[16 + c16] = mhi;
            }
            // same-wave ds_write -> ds_read; compiler inserts lgkmcnt

            // ======== GEMM: c = tanh(mean @ W); quarter rg covers k in [32rg, 32rg+32) ========
            float4 plo = make_float4(0.f,0.f,0.f,0.f), phi = plo;
#pragma unroll
            for (int jq = 0; jq < 8; ++jq) {
                const float4 m4 = mb[(rg << 3) + jq];
                const int kb = (rg << 5) + (jq << 2);
#define FMAK(mm, kk)                                                           \
                {                                                              \
                    const uint32_t* rowp = &sWb[(kk) * WSTRIDE];               \
                    const uint2 ul = *(const uint2*)&rowp[wco];                \
                    const uint2 uh = *(const uint2*)&rowp[32 + wco];           \
                    plo.x = fmaf(mm, __uint_as_float(ul.x << 16),         plo.x); \
                    plo.y = fmaf(mm, __uint_as_float(ul.x & 0xFFFF0000u), plo.y); \
                    plo.z = fmaf(mm, __uint_as_float(ul.y << 16),         plo.z); \
                    plo.w = fmaf(mm, __uint_as_float(ul.y & 0xFFFF0000u), plo.w); \
                    phi.x = fmaf(mm, __uint_as_float(uh.x << 16),         phi.x); \
                    phi.y = fmaf(mm, __uint_as_float(uh.x & 0xFFFF0000u), phi.y); \
                    phi.z = fmaf(mm, __uint_as_float(uh.y << 16),         phi.z); \
                    phi.w = fmaf(mm, __uint_as_float(uh.y & 0xFFFF0000u), phi.w); \
                }
                FMAK(m4.x, kb + 0); FMAK(m4.y, kb + 1);
                FMAK(m4.z, kb + 2); FMAK(m4.w, kb + 3);
#undef FMAK
            }
            plo = f4add(plo, f4shfl_xor(plo, 16));
            plo = f4add(plo, f4shfl_xor(plo, 32));
            phi = f4add(phi, f4shfl_xor(phi, 16));
            phi = f4add(phi, f4shfl_xor(phi, 32));
            float4 clo, chi;
            clo.x = fast_tanh(plo.x); clo.y = fast_tanh(plo.y);
            clo.z = fast_tanh(plo.z); clo.w = fast_tanh(plo.w);
            chi.x = fast_tanh(phi.x); chi.y = fast_tanh(phi.y);
            chi.z = fast_tanh(phi.z); chi.w = fast_tanh(phi.w);

            // ======== pass 2: gates + h from bf16 regs; DPP-only row reduction ========
            float4 hlo = make_float4(0.f,0.f,0.f,0.f), hhi = hlo;
#pragma unroll
            for (int sl = 0; sl < MAXSLOT; ++sl) {
                const float4 lo = unpack4(rbPk[sl].x, rbPk[sl].y);
                const float4 hi = unpack4(rbPk[sl].z, rbPk[sl].w);
                float d = dot8(lo, hi, clo, chi);
                d = row16_sum(d);
                const float g = fast_sigmoid(d);       // masked rows staged as 0 -> g*0
                hlo.x = fmaf(g, lo.x, hlo.x); hlo.y = fmaf(g, lo.y, hlo.y);
                hlo.z = fmaf(g, lo.z, hlo.z); hlo.w = fmaf(g, lo.w, hlo.w);
                hhi.x = fmaf(g, hi.x, hhi.x); hhi.y = fmaf(g, hi.y, hhi.y);
                hhi.z = fmaf(g, hi.z, hhi.z); hhi.w = fmaf(g, hi.w, hhi.w);
            }
            // tail rows > 48: re-read from global (L2-hot from the sum tail), rare
            for (int i = s + NROW + rg; i < e; i += 4) {
                const float4 lo = x4[(size_t)i * 32 + c16];
                const float4 hi = x4[(size_t)i * 32 + 16 + c16];
                float d = dot8(lo, hi, clo, chi);
                d = row16_sum(d);
                const float g = fast_sigmoid(d);
                hlo.x = fmaf(g, lo.x, hlo.x); hlo.y = fmaf(g, lo.y, hlo.y);
                hlo.z = fmaf(g, lo.z, hlo.z); hlo.w = fmaf(g, lo.w, hlo.w);
                hhi.x = fmaf(g, hi.x, hhi.x); hhi.y = fmaf(g, hi.y, hhi.y);
                hhi.z = fmaf(g, hi.z, hhi.z); hhi.w = fmaf(g, hi.w, hhi.w);
            }
            hlo = f4add(hlo, f4shfl_xor(hlo, 16));
            hlo = f4add(hlo, f4shfl_xor(hlo, 32));
            hhi = f4add(hhi, f4shfl_xor(hhi, 16));
            hhi = f4add(hhi, f4shfl_xor(hhi, 32));
            if (lane < 16) {
                ((float4*)out)[(size_t)b * 32 + c16]      = hlo;
                ((float4*)out)[(size_t)b * 32 + 16 + c16] = hhi;
            }
        }
#undef ISSUE
    }
}

extern "C" void kernel_launch(void* const* d_in, const int* in_sizes, int n_in,
                              void* d_out, int out_size, void* d_ws, size_t ws_size,
                              hipStream_t stream) {
    const float* x     = (const float*)d_in[0];
    const float* W     = (const float*)d_in[1];
    const int*   batch = (const int*)d_in[2];
    float*       out   = (float*)d_out;

    const int N = in_sizes[0] / C;   // 2,000,000
    const int B = out_size / C;      // 50,000

    const int grid = 512;            // 2 blocks/CU (37 KB LDS each), 8 waves/CU
    hipLaunchKernelGGL(cba_blkloc_kernel, dim3(grid), dim3(BLK), 0, stream,
                       x, W, batch, out, N, B, grid);
}